// Round 8
// baseline (556.095 us; speedup 1.0000x reference)
//
#include <hip/hip_runtime.h>
#include <hip/hip_bf16.h>

typedef __bf16 bf16_t;
typedef __bf16 bf16x8 __attribute__((ext_vector_type(8)));
typedef __bf16 bf16x4 __attribute__((ext_vector_type(4)));
typedef float f32x4 __attribute__((ext_vector_type(4)));

static constexpr int E = 1024;
static constexpr int BROWS = 16384;
static constexpr size_t MB = 1ull << 20;

__device__ __forceinline__ float gelu_f(float x) {
  float t = __expf(-x * fmaf(0.0713548163f, x * x, 1.5957691216f));
  return x / (1.0f + t);
}

// ---------------- f32 -> bf16 convert ----------------
__global__ __launch_bounds__(256) void cvt_f32_bf16(const float* __restrict__ src,
                                                    bf16_t* __restrict__ dst, int n4) {
  int stride = gridDim.x * blockDim.x;
  for (int i = blockIdx.x * blockDim.x + threadIdx.x; i < n4; i += stride) {
    float4 v = reinterpret_cast<const float4*>(src)[i];
    bf16x4 o;
    o[0] = (bf16_t)v.x; o[1] = (bf16_t)v.y; o[2] = (bf16_t)v.z; o[3] = (bf16_t)v.w;
    reinterpret_cast<bf16x4*>(dst)[i] = o;
  }
}

// ---------------- f32 -> bf16 transposed convert (1024x1024) ----------------
__global__ __launch_bounds__(256) void cvt_transpose(const float* __restrict__ in,
                                                     bf16_t* __restrict__ out) {
  __shared__ float t[64][65];
  const int bx = blockIdx.x * 64, by = blockIdx.y * 64;
  const int tid = threadIdx.x;
  const int r = tid >> 2, c4 = (tid & 3) * 16;
#pragma unroll
  for (int j = 0; j < 4; ++j) {
    float4 v = *reinterpret_cast<const float4*>(&in[(long)(by + r) * E + bx + c4 + j * 4]);
    t[r][c4 + j * 4 + 0] = v.x;
    t[r][c4 + j * 4 + 1] = v.y;
    t[r][c4 + j * 4 + 2] = v.z;
    t[r][c4 + j * 4 + 3] = v.w;
  }
  __syncthreads();
#pragma unroll
  for (int j = 0; j < 16; j += 4) {
    bf16x4 o;
    o[0] = (bf16_t)t[c4 + j + 0][r];
    o[1] = (bf16_t)t[c4 + j + 1][r];
    o[2] = (bf16_t)t[c4 + j + 2][r];
    o[3] = (bf16_t)t[c4 + j + 3][r];
    *reinterpret_cast<bf16x4*>(&out[(long)(bx + r) * E + by + c4 + j]) = o;
  }
}

// ---------------- fused bias: outb[n] = dot(wo[n,:], bv) + bo[n] ----------------
__global__ __launch_bounds__(256) void fuse_bias(const float* __restrict__ wo,
                                                 const float* __restrict__ bv,
                                                 const float* __restrict__ bo,
                                                 float* __restrict__ outb) {
  const int row = (blockIdx.x * 256 + threadIdx.x) >> 6;
  const int lane = threadIdx.x & 63;
  float s = 0.f;
  for (int k = lane; k < E; k += 64) s += wo[(long)row * E + k] * bv[k];
#pragma unroll
  for (int off = 32; off; off >>= 1) s += __shfl_down(s, off);
  if (lane == 0) outb[row] = s + bo[row];
}

// ---------------- small bf16 GEMM (128x128 tile, m97 structure) for Wc ----------------
__global__ __launch_bounds__(256) void gemm_bt_small(const bf16_t* __restrict__ A,
                                                     const bf16_t* __restrict__ Bw,
                                                     bf16_t* __restrict__ Cout, int K, int N,
                                                     int NBX) {
  const int nwg = gridDim.x;
  const int orig = blockIdx.x;
  const int q = nwg >> 3;
  const int wgid = (orig & 7) * q + (orig >> 3);
  const int bx = wgid % NBX;
  const int by = wgid / NBX;
  __shared__ bf16_t As[128 * 32];
  __shared__ bf16_t Bs[128 * 32];
  const int tid = threadIdx.x;
  const int lane = tid & 63;
  const int w = tid >> 6;
  const int wr = w >> 1, wc = w & 1;
  const long m0 = (long)by * 128;
  const long n0 = (long)bx * 128;
  const bf16_t* aSrc = A + (m0 + (tid >> 2)) * (long)K + (tid & 3) * 8;
  const bf16_t* bSrc = Bw + (n0 + (tid >> 2)) * (long)K + (tid & 3) * 8;
  f32x4 acc[4][4];
#pragma unroll
  for (int mi = 0; mi < 4; ++mi)
#pragma unroll
    for (int ni = 0; ni < 4; ++ni) acc[mi][ni] = {0.f, 0.f, 0.f, 0.f};
  const int nkt = K >> 5;
  for (int kt = 0; kt < nkt; ++kt) {
#pragma unroll
    for (int r = 0; r < 2; ++r) {
      __builtin_amdgcn_global_load_lds(
          (__attribute__((address_space(1))) void*)(aSrc + (long)r * 64 * K + kt * 32),
          (__attribute__((address_space(3))) void*)((char*)As + r * 4096 + w * 1024), 16, 0, 0);
      __builtin_amdgcn_global_load_lds(
          (__attribute__((address_space(1))) void*)(bSrc + (long)r * 64 * K + kt * 32),
          (__attribute__((address_space(3))) void*)((char*)Bs + r * 4096 + w * 1024), 16, 0, 0);
    }
    __syncthreads();
    bf16x8 af[4], bfv[4];
#pragma unroll
    for (int i = 0; i < 4; ++i) {
      af[i] = *reinterpret_cast<const bf16x8*>(
          &As[(wr * 64 + i * 16 + (lane & 15)) * 32 + (lane >> 4) * 8]);
      bfv[i] = *reinterpret_cast<const bf16x8*>(
          &Bs[(wc * 64 + i * 16 + (lane & 15)) * 32 + (lane >> 4) * 8]);
    }
#pragma unroll
    for (int mi = 0; mi < 4; ++mi)
#pragma unroll
      for (int ni = 0; ni < 4; ++ni)
        acc[mi][ni] = __builtin_amdgcn_mfma_f32_16x16x32_bf16(af[mi], bfv[ni], acc[mi][ni], 0, 0, 0);
    __syncthreads();
  }
  const long crow0 = m0 + wr * 64 + ((lane >> 4) * 4);
  const long ccol0 = n0 + wc * 64 + (lane & 15);
#pragma unroll
  for (int mi = 0; mi < 4; ++mi)
#pragma unroll
    for (int ni = 0; ni < 4; ++ni)
#pragma unroll
      for (int r = 0; r < 4; ++r)
        Cout[(crow0 + mi * 16 + r) * N + ccol0 + ni * 16] = (bf16_t)acc[mi][ni][r];
}

// ============ 256x256 tile, 8-wave, ring-4-slot, m201-style 8-phase bf16 GEMM ============
// Per slot (BK=32): two phases, each {ds_read frags; 2 glds; [counted vmcnt]; s_barrier;
// lgkmcnt(0)+sched_barrier; setprio(1); 16 MFMA; setprio(0); s_barrier}.
// Ring/staging/wait arithmetic identical to the R5-proven schedule (stage j+3, vmcnt 8/4/0).
#define GLDS(gp, lp)                                                              \
  __builtin_amdgcn_global_load_lds((__attribute__((address_space(1))) void*)(gp), \
                                   (__attribute__((address_space(3))) void*)(lp), 16, 0, 0)

template <int ACT_GELU, int OUT_BF16>
__global__ __launch_bounds__(512) void gemm256(const bf16_t* __restrict__ A,
                                               const bf16_t* __restrict__ Bw,
                                               const float* __restrict__ bias,
                                               void* __restrict__ Cout, int K, int N, int NBX) {
  __shared__ char smem[131072];
  const int nwg = gridDim.x;
  const int orig = blockIdx.x;
  const int q = nwg >> 3;
  const int wgid = (orig & 7) * q + (orig >> 3);  // bijective for nwg%8==0
  const int bx = wgid % NBX;
  const int by = wgid / NBX;
  const long m0 = (long)by * 256;
  const long n0 = (long)bx * 256;

  const int tid = threadIdx.x;
  const int lane = tid & 63;
  const int w = tid >> 6;       // 8 waves
  const int wr = w >> 2;        // 0..1 -> rows wr*128
  const int wc = w & 3;         // 0..3 -> cols wc*64

  // ---- staging source (inverse-swizzled global addresses) ----
  const int sv = (lane & 7) ^ (lane >> 3);
  const int r2 = (lane >> 3) * 2 + (sv >> 2);
  const int kc = (sv & 3) * 8;
  const bf16_t* srcA0 = A + (m0 + w * 32 + r2) * (long)K + kc;
  const bf16_t* srcA1 = srcA0 + 16 * (long)K;
  const bf16_t* srcB0 = Bw + (n0 + w * 32 + r2) * (long)K + kc;
  const bf16_t* srcB1 = srcB0 + 16 * (long)K;

#define STAGE_A(s, t)                                                   \
  {                                                                     \
    GLDS(srcA0 + (long)(t) * 32, smem + (s) * 32768 + w * 2048);        \
    GLDS(srcA1 + (long)(t) * 32, smem + (s) * 32768 + w * 2048 + 1024); \
  }
#define STAGE_B(s, t)                                                           \
  {                                                                             \
    GLDS(srcB0 + (long)(t) * 32, smem + (s) * 32768 + 16384 + w * 2048);        \
    GLDS(srcB1 + (long)(t) * 32, smem + (s) * 32768 + 16384 + w * 2048 + 1024); \
  }

  // ---- fragment-read lane offset (swizzled, conflict-free; verified R5) ----
  const int laneoff =
      ((lane >> 1) & 7) * 128 +
      ((((((lane & 1) << 2) | (lane >> 4))) ^ ((lane >> 1) & 7)) << 4);
  const int wrOff = wr * 8192;   // A: 128 rows * 64B
  const int wcOff = wc * 4096;   // B: 64 rows * 64B

  f32x4 acc[8][4];
#pragma unroll
  for (int mi = 0; mi < 8; ++mi)
#pragma unroll
    for (int ni = 0; ni < 4; ++ni) acc[mi][ni] = {0.f, 0.f, 0.f, 0.f};

  // prologue: stage slots 0..2 (12 loads/wave), certify slot 0 for all waves
  STAGE_A(0, 0); STAGE_B(0, 0);
  STAGE_A(1, 1); STAGE_B(1, 1);
  STAGE_A(2, 2); STAGE_B(2, 2);
  asm volatile("s_waitcnt vmcnt(8)" ::: "memory");
  asm volatile("s_barrier" ::: "memory");

  const int NS = K >> 5;
#pragma unroll 1
  for (int j = 0; j < NS; ++j) {
    const char* sb = smem + (j & 3) * 32768;

    // ================= phase A: m-frags 0..3 =================
    if (j + 3 < NS) STAGE_A((j + 3) & 3, j + 3);
    bf16x8 a[4], b[4];
#pragma unroll
    for (int i = 0; i < 4; ++i)
      a[i] = *reinterpret_cast<const bf16x8*>(sb + wrOff + i * 1024 + laneoff);
#pragma unroll
    for (int i = 0; i < 4; ++i)
      b[i] = *reinterpret_cast<const bf16x8*>(sb + 16384 + wcOff + i * 1024 + laneoff);
    asm volatile("s_barrier" ::: "memory");
    asm volatile("s_waitcnt lgkmcnt(0)" ::: "memory");
    __builtin_amdgcn_sched_barrier(0);
    __builtin_amdgcn_s_setprio(1);
#pragma unroll
    for (int mi = 0; mi < 4; ++mi)
#pragma unroll
      for (int ni = 0; ni < 4; ++ni)
        acc[mi][ni] = __builtin_amdgcn_mfma_f32_16x16x32_bf16(a[mi], b[ni], acc[mi][ni], 0, 0, 0);
    __builtin_amdgcn_s_setprio(0);
    asm volatile("s_barrier" ::: "memory");

    // ================= phase B: m-frags 4..7 (reuse b) =================
    if (j + 3 < NS) STAGE_B((j + 3) & 3, j + 3);
    bf16x8 a2[4];
#pragma unroll
    for (int i = 0; i < 4; ++i)
      a2[i] = *reinterpret_cast<const bf16x8*>(sb + wrOff + (4 + i) * 1024 + laneoff);
    // counted wait certifying slot j+1 for ALL waves (before the barrier)
    if (j + 1 < NS) {
      if (j <= NS - 4)
        asm volatile("s_waitcnt vmcnt(8)" ::: "memory");
      else if (j == NS - 3)
        asm volatile("s_waitcnt vmcnt(4)" ::: "memory");
      else
        asm volatile("s_waitcnt vmcnt(0)" ::: "memory");
    }
    asm volatile("s_barrier" ::: "memory");
    asm volatile("s_waitcnt lgkmcnt(0)" ::: "memory");
    __builtin_amdgcn_sched_barrier(0);
    __builtin_amdgcn_s_setprio(1);
#pragma unroll
    for (int mi = 0; mi < 4; ++mi)
#pragma unroll
      for (int ni = 0; ni < 4; ++ni)
        acc[4 + mi][ni] =
            __builtin_amdgcn_mfma_f32_16x16x32_bf16(a2[mi], b[ni], acc[4 + mi][ni], 0, 0, 0);
    __builtin_amdgcn_s_setprio(0);
    asm volatile("s_barrier" ::: "memory");
  }

  // ---- epilogue: bias + (gelu) + direct store ----
  float bv[4];
#pragma unroll
  for (int ni = 0; ni < 4; ++ni) bv[ni] = bias[n0 + wc * 64 + ni * 16 + (lane & 15)];
  const long crow0 = m0 + wr * 128 + ((lane >> 4) * 4);
  const long ccol0 = n0 + wc * 64 + (lane & 15);
#pragma unroll
  for (int mi = 0; mi < 8; ++mi) {
#pragma unroll
    for (int ni = 0; ni < 4; ++ni) {
#pragma unroll
      for (int rr = 0; rr < 4; ++rr) {
        float v = acc[mi][ni][rr] + bv[ni];
        if (ACT_GELU) v = gelu_f(v);
        long idx = (crow0 + mi * 16 + rr) * N + ccol0 + ni * 16;
        if (OUT_BF16)
          ((bf16_t*)Cout)[idx] = (bf16_t)v;
        else
          ((float*)Cout)[idx] = v;
      }
    }
  }
}
#undef STAGE_A
#undef STAGE_B
#undef GLDS

// ---------------- fused residual-add + LayerNorm ----------------
template <int MODE>
__global__ __launch_bounds__(256) void ln_k(const float* __restrict__ Xf,
                                            const bf16_t* __restrict__ Xb,
                                            const float* __restrict__ Yf,
                                            const bf16_t* __restrict__ Yb,
                                            const float* __restrict__ gamma,
                                            const float* __restrict__ beta,
                                            const bf16_t* __restrict__ addB,
                                            float* __restrict__ outF,
                                            bf16_t* __restrict__ outB) {
  const int tid = threadIdx.x;
  const long base = (long)blockIdx.x * E;
  float4 s;
  if (MODE < 2) {
    float4 xv = reinterpret_cast<const float4*>(Xf + base)[tid];
    bf16x4 yv = reinterpret_cast<const bf16x4*>(Yb + base)[tid];
    s.x = xv.x + (float)yv[0]; s.y = xv.y + (float)yv[1];
    s.z = xv.z + (float)yv[2]; s.w = xv.w + (float)yv[3];
  } else {
    bf16x4 xv = reinterpret_cast<const bf16x4*>(Xb + base)[tid];
    float4 yv = reinterpret_cast<const float4*>(Yf + base)[tid];
    s.x = (float)xv[0] + yv.x; s.y = (float)xv[1] + yv.y;
    s.z = (float)xv[2] + yv.z; s.w = (float)xv[3] + yv.w;
  }
  float sum = s.x + s.y + s.z + s.w;
  float sq = s.x * s.x + s.y * s.y + s.z * s.z + s.w * s.w;
#pragma unroll
  for (int off = 32; off > 0; off >>= 1) {
    sum += __shfl_down(sum, off);
    sq += __shfl_down(sq, off);
  }
  __shared__ float red[2][4];
  const int w = tid >> 6;
  if ((tid & 63) == 0) { red[0][w] = sum; red[1][w] = sq; }
  __syncthreads();
  float tot = red[0][0] + red[0][1] + red[0][2] + red[0][3];
  float tsq = red[1][0] + red[1][1] + red[1][2] + red[1][3];
  const float mu = tot * (1.0f / E);
  const float var = tsq * (1.0f / E) - mu * mu;
  const float rs = rsqrtf(var + 1e-5f);
  float4 gv = reinterpret_cast<const float4*>(gamma)[tid];
  float4 bvv = reinterpret_cast<const float4*>(beta)[tid];
  float4 o;
  o.x = (s.x - mu) * rs * gv.x + bvv.x;
  o.y = (s.y - mu) * rs * gv.y + bvv.y;
  o.z = (s.z - mu) * rs * gv.z + bvv.z;
  o.w = (s.w - mu) * rs * gv.w + bvv.w;
  if (MODE == 1) {
    bf16x4 av = reinterpret_cast<const bf16x4*>(addB + base)[tid];
    o.x += (float)av[0]; o.y += (float)av[1]; o.z += (float)av[2]; o.w += (float)av[3];
  }
  if (MODE == 2) {
    reinterpret_cast<float4*>(outF + base)[tid] = o;
  } else {
    bf16x4 ob;
    ob[0] = (bf16_t)o.x; ob[1] = (bf16_t)o.y; ob[2] = (bf16_t)o.z; ob[3] = (bf16_t)o.w;
    reinterpret_cast<bf16x4*>(outB + base)[tid] = ob;
  }
}

extern "C" void kernel_launch(void* const* d_in, const int* in_sizes, int n_in, void* d_out,
                              int out_size, void* d_ws, size_t ws_size, hipStream_t stream) {
  const float* img_feat = (const float*)d_in[0];
  const float* txt_feat = (const float*)d_in[1];
  const float* w_in1 = (const float*)d_in[2];
  const float* b_in1 = (const float*)d_in[3];
  const float* w_out1 = (const float*)d_in[4];
  const float* b_out1 = (const float*)d_in[5];
  const float* w_in2 = (const float*)d_in[6];
  const float* b_in2 = (const float*)d_in[7];
  const float* w_out2 = (const float*)d_in[8];
  const float* b_out2 = (const float*)d_in[9];
  const float* g1 = (const float*)d_in[10];
  const float* be1 = (const float*)d_in[11];
  const float* g2 = (const float*)d_in[12];
  const float* be2 = (const float*)d_in[13];
  const float* g3 = (const float*)d_in[14];
  const float* be3 = (const float*)d_in[15];
  const float* w_ffn1 = (const float*)d_in[16];
  const float* b_ffn1 = (const float*)d_in[17];
  const float* w_ffn2 = (const float*)d_in[18];
  const float* b_ffn2 = (const float*)d_in[19];

  if (ws_size < 184 * MB) return;
  char* ws = (char*)d_ws;
  bf16_t* TXTB = (bf16_t*)(ws + 0 * MB);
  bf16_t* ATT = (bf16_t*)(ws + 32 * MB);
  bf16_t* IMGB = (bf16_t*)(ws + 64 * MB);
  bf16_t* H = (bf16_t*)(ws + 0 * MB);
  bf16_t* COMB = (bf16_t*)(ws + 128 * MB);
  bf16_t* T0 = (bf16_t*)(ws + 160 * MB);
  bf16_t* T1 = (bf16_t*)(ws + 162 * MB);
  bf16_t* Wc1 = (bf16_t*)(ws + 164 * MB);
  bf16_t* Wc2 = (bf16_t*)(ws + 166 * MB);
  bf16_t* wf1b = (bf16_t*)(ws + 168 * MB);
  bf16_t* wf2b = (bf16_t*)(ws + 176 * MB);
  float* bias1 = (float*)d_out;
  float* bias2 = bias1 + E;

  dim3 blk(256);
  dim3 blk512(512);
  cvt_f32_bf16<<<dim3(2048), blk, 0, stream>>>(txt_feat, TXTB, BROWS * E / 4);
  cvt_f32_bf16<<<dim3(1024), blk, 0, stream>>>(w_ffn1, wf1b, 4 * E * E / 4);
  cvt_f32_bf16<<<dim3(1024), blk, 0, stream>>>(w_ffn2, wf2b, 4 * E * E / 4);

  // Wc1 = wo1 @ wv1, bias1 = wo1 @ bv1 + bo1
  cvt_transpose<<<dim3(16, 16), blk, 0, stream>>>(w_in1 + 2 * E * E, T0);
  cvt_f32_bf16<<<dim3(512), blk, 0, stream>>>(w_out1, T1, E * E / 4);
  gemm_bt_small<<<dim3(64), blk, 0, stream>>>(T1, T0, Wc1, E, E, 8);
  fuse_bias<<<dim3(256), blk, 0, stream>>>(w_out1, b_in1 + 2 * E, b_out1, bias1);

  // Wc2 = wo2 @ wv2, bias2 = wo2 @ bv2 + bo2
  cvt_transpose<<<dim3(16, 16), blk, 0, stream>>>(w_in2 + 2 * E * E, T0);
  cvt_f32_bf16<<<dim3(512), blk, 0, stream>>>(w_out2, T1, E * E / 4);
  gemm_bt_small<<<dim3(64), blk, 0, stream>>>(T1, T0, Wc2, E, E, 8);
  fuse_bias<<<dim3(256), blk, 0, stream>>>(w_out2, b_in2 + 2 * E, b_out2, bias2);

  // G12: att1 = txt @ Wc1^T + bias1
  gemm256<0, 1><<<dim3(256), blk512, 0, stream>>>(TXTB, Wc1, bias1, ATT, E, E, 4);
  // LN1: img = LN(img_feat + att1)
  ln_k<0><<<dim3(BROWS), blk, 0, stream>>>(img_feat, nullptr, nullptr, ATT, g1, be1, nullptr,
                                           nullptr, IMGB);
  // G34: att2 = img @ Wc2^T + bias2
  gemm256<0, 1><<<dim3(256), blk512, 0, stream>>>(IMGB, Wc2, bias2, ATT, E, E, 4);
  // LN2: comb = img + LN(txt_feat + att2)
  ln_k<1><<<dim3(BROWS), blk, 0, stream>>>(txt_feat, nullptr, nullptr, ATT, g2, be2, IMGB,
                                           nullptr, COMB);
  // G5: h = gelu(comb @ wf1^T + b_ffn1)
  gemm256<1, 1><<<dim3(1024), blk512, 0, stream>>>(COMB, wf1b, b_ffn1, H, E, 4 * E, 16);
  // G6: ffn = h @ wf2^T + b_ffn2 -> d_out (f32)
  gemm256<0, 0><<<dim3(256), blk512, 0, stream>>>(H, wf2b, b_ffn2, d_out, 4 * E, E, 4);
  // LN3: out = LN(comb + ffn), in place on d_out
  ln_k<2><<<dim3(BROWS), blk, 0, stream>>>(nullptr, COMB, (float*)d_out, nullptr, g3, be3,
                                           nullptr, (float*)d_out, nullptr);
}

// Round 9
// 552.311 us; speedup vs baseline: 1.0069x; 1.0069x over previous
//
#include <hip/hip_runtime.h>
#include <hip/hip_bf16.h>

typedef __bf16 bf16_t;
typedef __bf16 bf16x8 __attribute__((ext_vector_type(8)));
typedef __bf16 bf16x4 __attribute__((ext_vector_type(4)));
typedef float f32x4 __attribute__((ext_vector_type(4)));

static constexpr int E = 1024;
static constexpr int BROWS = 16384;
static constexpr size_t MB = 1ull << 20;

__device__ __forceinline__ float gelu_f(float x) {
  float t = __expf(-x * fmaf(0.0713548163f, x * x, 1.5957691216f));
  return x / (1.0f + t);
}

// ---------------- f32 -> bf16 convert ----------------
__global__ __launch_bounds__(256) void cvt_f32_bf16(const float* __restrict__ src,
                                                    bf16_t* __restrict__ dst, int n4) {
  int stride = gridDim.x * blockDim.x;
  for (int i = blockIdx.x * blockDim.x + threadIdx.x; i < n4; i += stride) {
    float4 v = reinterpret_cast<const float4*>(src)[i];
    bf16x4 o;
    o[0] = (bf16_t)v.x; o[1] = (bf16_t)v.y; o[2] = (bf16_t)v.z; o[3] = (bf16_t)v.w;
    reinterpret_cast<bf16x4*>(dst)[i] = o;
  }
}

// ---------------- f32 -> bf16 transposed convert (1024x1024) ----------------
__global__ __launch_bounds__(256) void cvt_transpose(const float* __restrict__ in,
                                                     bf16_t* __restrict__ out) {
  __shared__ float t[64][65];
  const int bx = blockIdx.x * 64, by = blockIdx.y * 64;
  const int tid = threadIdx.x;
  const int r = tid >> 2, c4 = (tid & 3) * 16;
#pragma unroll
  for (int j = 0; j < 4; ++j) {
    float4 v = *reinterpret_cast<const float4*>(&in[(long)(by + r) * E + bx + c4 + j * 4]);
    t[r][c4 + j * 4 + 0] = v.x;
    t[r][c4 + j * 4 + 1] = v.y;
    t[r][c4 + j * 4 + 2] = v.z;
    t[r][c4 + j * 4 + 3] = v.w;
  }
  __syncthreads();
#pragma unroll
  for (int j = 0; j < 16; j += 4) {
    bf16x4 o;
    o[0] = (bf16_t)t[c4 + j + 0][r];
    o[1] = (bf16_t)t[c4 + j + 1][r];
    o[2] = (bf16_t)t[c4 + j + 2][r];
    o[3] = (bf16_t)t[c4 + j + 3][r];
    *reinterpret_cast<bf16x4*>(&out[(long)(bx + r) * E + by + c4 + j]) = o;
  }
}

// ---------------- fused bias: outb[n] = dot(wo[n,:], bv) + bo[n] ----------------
__global__ __launch_bounds__(256) void fuse_bias(const float* __restrict__ wo,
                                                 const float* __restrict__ bv,
                                                 const float* __restrict__ bo,
                                                 float* __restrict__ outb) {
  const int row = (blockIdx.x * 256 + threadIdx.x) >> 6;
  const int lane = threadIdx.x & 63;
  float s = 0.f;
  for (int k = lane; k < E; k += 64) s += wo[(long)row * E + k] * bv[k];
#pragma unroll
  for (int off = 32; off; off >>= 1) s += __shfl_down(s, off);
  if (lane == 0) outb[row] = s + bo[row];
}

// ---------------- small bf16 GEMM (128x128 tile, m97 structure) for Wc ----------------
__global__ __launch_bounds__(256) void gemm_bt_small(const bf16_t* __restrict__ A,
                                                     const bf16_t* __restrict__ Bw,
                                                     bf16_t* __restrict__ Cout, int K, int N,
                                                     int NBX) {
  const int nwg = gridDim.x;
  const int orig = blockIdx.x;
  const int q = nwg >> 3;
  const int wgid = (orig & 7) * q + (orig >> 3);
  const int bx = wgid % NBX;
  const int by = wgid / NBX;
  __shared__ bf16_t As[128 * 32];
  __shared__ bf16_t Bs[128 * 32];
  const int tid = threadIdx.x;
  const int lane = tid & 63;
  const int w = tid >> 6;
  const int wr = w >> 1, wc = w & 1;
  const long m0 = (long)by * 128;
  const long n0 = (long)bx * 128;
  const bf16_t* aSrc = A + (m0 + (tid >> 2)) * (long)K + (tid & 3) * 8;
  const bf16_t* bSrc = Bw + (n0 + (tid >> 2)) * (long)K + (tid & 3) * 8;
  f32x4 acc[4][4];
#pragma unroll
  for (int mi = 0; mi < 4; ++mi)
#pragma unroll
    for (int ni = 0; ni < 4; ++ni) acc[mi][ni] = {0.f, 0.f, 0.f, 0.f};
  const int nkt = K >> 5;
  for (int kt = 0; kt < nkt; ++kt) {
#pragma unroll
    for (int r = 0; r < 2; ++r) {
      __builtin_amdgcn_global_load_lds(
          (__attribute__((address_space(1))) void*)(aSrc + (long)r * 64 * K + kt * 32),
          (__attribute__((address_space(3))) void*)((char*)As + r * 4096 + w * 1024), 16, 0, 0);
      __builtin_amdgcn_global_load_lds(
          (__attribute__((address_space(1))) void*)(bSrc + (long)r * 64 * K + kt * 32),
          (__attribute__((address_space(3))) void*)((char*)Bs + r * 4096 + w * 1024), 16, 0, 0);
    }
    __syncthreads();
    bf16x8 af[4], bfv[4];
#pragma unroll
    for (int i = 0; i < 4; ++i) {
      af[i] = *reinterpret_cast<const bf16x8*>(
          &As[(wr * 64 + i * 16 + (lane & 15)) * 32 + (lane >> 4) * 8]);
      bfv[i] = *reinterpret_cast<const bf16x8*>(
          &Bs[(wc * 64 + i * 16 + (lane & 15)) * 32 + (lane >> 4) * 8]);
    }
#pragma unroll
    for (int mi = 0; mi < 4; ++mi)
#pragma unroll
      for (int ni = 0; ni < 4; ++ni)
        acc[mi][ni] = __builtin_amdgcn_mfma_f32_16x16x32_bf16(af[mi], bfv[ni], acc[mi][ni], 0, 0, 0);
    __syncthreads();
  }
  const long crow0 = m0 + wr * 64 + ((lane >> 4) * 4);
  const long ccol0 = n0 + wc * 64 + (lane & 15);
#pragma unroll
  for (int mi = 0; mi < 4; ++mi)
#pragma unroll
    for (int ni = 0; ni < 4; ++ni)
#pragma unroll
      for (int r = 0; r < 4; ++r)
        Cout[(crow0 + mi * 16 + r) * N + ccol0 + ni * 16] = (bf16_t)acc[mi][ni][r];
}

// ============ 256x256 tile, 8-wave, ring-4-slot bf16 GEMM with reg-dbuf prefetch ============
// Iter j: {stage slot j+3; ds_read slot j+1 frags into NEXT reg set; 32 MFMA on CUR set;
//          lgkmcnt(0); counted vmcnt certifying slot j+2; s_barrier}.
// ds_read latency hides under the wave's own MFMA cluster (ILP). Two-step unroll keeps
// all fragment-register indexing compile-time (rule 20). vmcnt(4) steady, 0 only at tail.
#define GLDS(gp, lp)                                                              \
  __builtin_amdgcn_global_load_lds((__attribute__((address_space(1))) void*)(gp), \
                                   (__attribute__((address_space(3))) void*)(lp), 16, 0, 0)

template <int ACT_GELU, int OUT_BF16>
__global__ __launch_bounds__(512) void gemm256(const bf16_t* __restrict__ A,
                                               const bf16_t* __restrict__ Bw,
                                               const float* __restrict__ bias,
                                               void* __restrict__ Cout, int K, int N, int NBX) {
  __shared__ char smem[131072];
  const int nwg = gridDim.x;
  const int orig = blockIdx.x;
  const int q = nwg >> 3;
  const int wgid = (orig & 7) * q + (orig >> 3);  // bijective for nwg%8==0
  const int bx = wgid % NBX;
  const int by = wgid / NBX;
  const long m0 = (long)by * 256;
  const long n0 = (long)bx * 256;

  const int tid = threadIdx.x;
  const int lane = tid & 63;
  const int w = tid >> 6;       // 8 waves
  const int wr = w >> 2;        // 0..1 -> rows wr*128
  const int wc = w & 3;         // 0..3 -> cols wc*64

  // ---- staging source (inverse-swizzled global addresses; R5-verified) ----
  const int sv = (lane & 7) ^ (lane >> 3);
  const int r2 = (lane >> 3) * 2 + (sv >> 2);
  const int kc = (sv & 3) * 8;
  const bf16_t* srcA0 = A + (m0 + w * 32 + r2) * (long)K + kc;
  const bf16_t* srcA1 = srcA0 + 16 * (long)K;
  const bf16_t* srcB0 = Bw + (n0 + w * 32 + r2) * (long)K + kc;
  const bf16_t* srcB1 = srcB0 + 16 * (long)K;

#define STAGE_A(s, t)                                                   \
  {                                                                     \
    GLDS(srcA0 + (long)(t) * 32, smem + (s) * 32768 + w * 2048);        \
    GLDS(srcA1 + (long)(t) * 32, smem + (s) * 32768 + w * 2048 + 1024); \
  }
#define STAGE_B(s, t)                                                           \
  {                                                                             \
    GLDS(srcB0 + (long)(t) * 32, smem + (s) * 32768 + 16384 + w * 2048);        \
    GLDS(srcB1 + (long)(t) * 32, smem + (s) * 32768 + 16384 + w * 2048 + 1024); \
  }

  // ---- fragment-read lane offset (swizzled, conflict-free; R5-verified) ----
  const int laneoff =
      ((lane >> 1) & 7) * 128 +
      ((((((lane & 1) << 2) | (lane >> 4))) ^ ((lane >> 1) & 7)) << 4);
  const int wrOff = wr * 8192;   // A: 128 rows * 64B
  const int wcOff = wc * 4096;   // B: 64 rows * 64B

#define RDFRAG(sidx, ar, br)                                                          \
  {                                                                                   \
    const char* sbp = smem + (sidx) * 32768;                                          \
    _Pragma("unroll") for (int i = 0; i < 8; ++i) ar[i] =                             \
        *reinterpret_cast<const bf16x8*>(sbp + wrOff + i * 1024 + laneoff);           \
    _Pragma("unroll") for (int i = 0; i < 4; ++i) br[i] =                             \
        *reinterpret_cast<const bf16x8*>(sbp + 16384 + wcOff + i * 1024 + laneoff);   \
  }

#define ITER(j, ca, cb, na, nb)                                                        \
  {                                                                                    \
    if ((j) + 3 < NS) { STAGE_A(((j) + 3) & 3, (j) + 3); STAGE_B(((j) + 3) & 3, (j) + 3); } \
    if ((j) + 1 < NS) RDFRAG(((j) + 1) & 3, na, nb);                                   \
    __builtin_amdgcn_s_setprio(1);                                                     \
    _Pragma("unroll") for (int mi = 0; mi < 8; ++mi)                                   \
        _Pragma("unroll") for (int ni = 0; ni < 4; ++ni) acc[mi][ni] =                 \
            __builtin_amdgcn_mfma_f32_16x16x32_bf16(ca[mi], cb[ni], acc[mi][ni], 0, 0, 0); \
    __builtin_amdgcn_s_setprio(0);                                                     \
    asm volatile("s_waitcnt lgkmcnt(0)" ::: "memory");                                 \
    if ((j) <= NS - 4)                                                                 \
      asm volatile("s_waitcnt vmcnt(4)" ::: "memory");                                 \
    else if ((j) == NS - 3)                                                            \
      asm volatile("s_waitcnt vmcnt(0)" ::: "memory");                                 \
    asm volatile("s_barrier" ::: "memory");                                            \
  }

  f32x4 acc[8][4];
#pragma unroll
  for (int mi = 0; mi < 8; ++mi)
#pragma unroll
    for (int ni = 0; ni < 4; ++ni) acc[mi][ni] = {0.f, 0.f, 0.f, 0.f};

  // prologue: stage slots 0..2 (12 loads/wave); certify slots 0 AND 1 for all waves
  STAGE_A(0, 0); STAGE_B(0, 0);
  STAGE_A(1, 1); STAGE_B(1, 1);
  STAGE_A(2, 2); STAGE_B(2, 2);
  asm volatile("s_waitcnt vmcnt(4)" ::: "memory");
  asm volatile("s_barrier" ::: "memory");

  const int NS = K >> 5;  // even for all K here (K = 1024 or 4096)
  bf16x8 aA[8], bA[4], aB[8], bB[4];
  RDFRAG(0, aA, bA);
#pragma unroll 1
  for (int j = 0; j < NS; j += 2) {
    ITER(j, aA, bA, aB, bB);
    ITER(j + 1, aB, bB, aA, bA);
  }

  // ---- epilogue: bias + (gelu) + direct store (proven) ----
  float bv[4];
#pragma unroll
  for (int ni = 0; ni < 4; ++ni) bv[ni] = bias[n0 + wc * 64 + ni * 16 + (lane & 15)];
  const long crow0 = m0 + wr * 128 + ((lane >> 4) * 4);
  const long ccol0 = n0 + wc * 64 + (lane & 15);
#pragma unroll
  for (int mi = 0; mi < 8; ++mi) {
#pragma unroll
    for (int ni = 0; ni < 4; ++ni) {
#pragma unroll
      for (int rr = 0; rr < 4; ++rr) {
        float v = acc[mi][ni][rr] + bv[ni];
        if (ACT_GELU) v = gelu_f(v);
        long idx = (crow0 + mi * 16 + rr) * N + ccol0 + ni * 16;
        if (OUT_BF16)
          ((bf16_t*)Cout)[idx] = (bf16_t)v;
        else
          ((float*)Cout)[idx] = v;
      }
    }
  }
#undef ITER
#undef RDFRAG
#undef STAGE_A
#undef STAGE_B
}
#undef GLDS

// ---------------- fused residual-add + LayerNorm ----------------
template <int MODE>
__global__ __launch_bounds__(256) void ln_k(const float* __restrict__ Xf,
                                            const bf16_t* __restrict__ Xb,
                                            const float* __restrict__ Yf,
                                            const bf16_t* __restrict__ Yb,
                                            const float* __restrict__ gamma,
                                            const float* __restrict__ beta,
                                            const bf16_t* __restrict__ addB,
                                            float* __restrict__ outF,
                                            bf16_t* __restrict__ outB) {
  const int tid = threadIdx.x;
  const long base = (long)blockIdx.x * E;
  float4 s;
  if (MODE < 2) {
    float4 xv = reinterpret_cast<const float4*>(Xf + base)[tid];
    bf16x4 yv = reinterpret_cast<const bf16x4*>(Yb + base)[tid];
    s.x = xv.x + (float)yv[0]; s.y = xv.y + (float)yv[1];
    s.z = xv.z + (float)yv[2]; s.w = xv.w + (float)yv[3];
  } else {
    bf16x4 xv = reinterpret_cast<const bf16x4*>(Xb + base)[tid];
    float4 yv = reinterpret_cast<const float4*>(Yf + base)[tid];
    s.x = (float)xv[0] + yv.x; s.y = (float)xv[1] + yv.y;
    s.z = (float)xv[2] + yv.z; s.w = (float)xv[3] + yv.w;
  }
  float sum = s.x + s.y + s.z + s.w;
  float sq = s.x * s.x + s.y * s.y + s.z * s.z + s.w * s.w;
#pragma unroll
  for (int off = 32; off > 0; off >>= 1) {
    sum += __shfl_down(sum, off);
    sq += __shfl_down(sq, off);
  }
  __shared__ float red[2][4];
  const int w = tid >> 6;
  if ((tid & 63) == 0) { red[0][w] = sum; red[1][w] = sq; }
  __syncthreads();
  float tot = red[0][0] + red[0][1] + red[0][2] + red[0][3];
  float tsq = red[1][0] + red[1][1] + red[1][2] + red[1][3];
  const float mu = tot * (1.0f / E);
  const float var = tsq * (1.0f / E) - mu * mu;
  const float rs = rsqrtf(var + 1e-5f);
  float4 gv = reinterpret_cast<const float4*>(gamma)[tid];
  float4 bvv = reinterpret_cast<const float4*>(beta)[tid];
  float4 o;
  o.x = (s.x - mu) * rs * gv.x + bvv.x;
  o.y = (s.y - mu) * rs * gv.y + bvv.y;
  o.z = (s.z - mu) * rs * gv.z + bvv.z;
  o.w = (s.w - mu) * rs * gv.w + bvv.w;
  if (MODE == 1) {
    bf16x4 av = reinterpret_cast<const bf16x4*>(addB + base)[tid];
    o.x += (float)av[0]; o.y += (float)av[1]; o.z += (float)av[2]; o.w += (float)av[3];
  }
  if (MODE == 2) {
    reinterpret_cast<float4*>(outF + base)[tid] = o;
  } else {
    bf16x4 ob;
    ob[0] = (bf16_t)o.x; ob[1] = (bf16_t)o.y; ob[2] = (bf16_t)o.z; ob[3] = (bf16_t)o.w;
    reinterpret_cast<bf16x4*>(outB + base)[tid] = ob;
  }
}

extern "C" void kernel_launch(void* const* d_in, const int* in_sizes, int n_in, void* d_out,
                              int out_size, void* d_ws, size_t ws_size, hipStream_t stream) {
  const float* img_feat = (const float*)d_in[0];
  const float* txt_feat = (const float*)d_in[1];
  const float* w_in1 = (const float*)d_in[2];
  const float* b_in1 = (const float*)d_in[3];
  const float* w_out1 = (const float*)d_in[4];
  const float* b_out1 = (const float*)d_in[5];
  const float* w_in2 = (const float*)d_in[6];
  const float* b_in2 = (const float*)d_in[7];
  const float* w_out2 = (const float*)d_in[8];
  const float* b_out2 = (const float*)d_in[9];
  const float* g1 = (const float*)d_in[10];
  const float* be1 = (const float*)d_in[11];
  const float* g2 = (const float*)d_in[12];
  const float* be2 = (const float*)d_in[13];
  const float* g3 = (const float*)d_in[14];
  const float* be3 = (const float*)d_in[15];
  const float* w_ffn1 = (const float*)d_in[16];
  const float* b_ffn1 = (const float*)d_in[17];
  const float* w_ffn2 = (const float*)d_in[18];
  const float* b_ffn2 = (const float*)d_in[19];

  if (ws_size < 184 * MB) return;
  char* ws = (char*)d_ws;
  bf16_t* TXTB = (bf16_t*)(ws + 0 * MB);
  bf16_t* ATT = (bf16_t*)(ws + 32 * MB);
  bf16_t* IMGB = (bf16_t*)(ws + 64 * MB);
  bf16_t* H = (bf16_t*)(ws + 0 * MB);
  bf16_t* COMB = (bf16_t*)(ws + 128 * MB);
  bf16_t* T0 = (bf16_t*)(ws + 160 * MB);
  bf16_t* T1 = (bf16_t*)(ws + 162 * MB);
  bf16_t* Wc1 = (bf16_t*)(ws + 164 * MB);
  bf16_t* Wc2 = (bf16_t*)(ws + 166 * MB);
  bf16_t* wf1b = (bf16_t*)(ws + 168 * MB);
  bf16_t* wf2b = (bf16_t*)(ws + 176 * MB);
  float* bias1 = (float*)d_out;
  float* bias2 = bias1 + E;

  dim3 blk(256);
  dim3 blk512(512);
  cvt_f32_bf16<<<dim3(2048), blk, 0, stream>>>(txt_feat, TXTB, BROWS * E / 4);
  cvt_f32_bf16<<<dim3(1024), blk, 0, stream>>>(w_ffn1, wf1b, 4 * E * E / 4);
  cvt_f32_bf16<<<dim3(1024), blk, 0, stream>>>(w_ffn2, wf2b, 4 * E * E / 4);

  // Wc1 = wo1 @ wv1, bias1 = wo1 @ bv1 + bo1
  cvt_transpose<<<dim3(16, 16), blk, 0, stream>>>(w_in1 + 2 * E * E, T0);
  cvt_f32_bf16<<<dim3(512), blk, 0, stream>>>(w_out1, T1, E * E / 4);
  gemm_bt_small<<<dim3(64), blk, 0, stream>>>(T1, T0, Wc1, E, E, 8);
  fuse_bias<<<dim3(256), blk, 0, stream>>>(w_out1, b_in1 + 2 * E, b_out1, bias1);

  // Wc2 = wo2 @ wv2, bias2 = wo2 @ bv2 + bo2
  cvt_transpose<<<dim3(16, 16), blk, 0, stream>>>(w_in2 + 2 * E * E, T0);
  cvt_f32_bf16<<<dim3(512), blk, 0, stream>>>(w_out2, T1, E * E / 4);
  gemm_bt_small<<<dim3(64), blk, 0, stream>>>(T1, T0, Wc2, E, E, 8);
  fuse_bias<<<dim3(256), blk, 0, stream>>>(w_out2, b_in2 + 2 * E, b_out2, bias2);

  // G12: att1 = txt @ Wc1^T + bias1
  gemm256<0, 1><<<dim3(256), blk512, 0, stream>>>(TXTB, Wc1, bias1, ATT, E, E, 4);
  // LN1: img = LN(img_feat + att1)
  ln_k<0><<<dim3(BROWS), blk, 0, stream>>>(img_feat, nullptr, nullptr, ATT, g1, be1, nullptr,
                                           nullptr, IMGB);
  // G34: att2 = img @ Wc2^T + bias2
  gemm256<0, 1><<<dim3(256), blk512, 0, stream>>>(IMGB, Wc2, bias2, ATT, E, E, 4);
  // LN2: comb = img + LN(txt_feat + att2)
  ln_k<1><<<dim3(BROWS), blk, 0, stream>>>(txt_feat, nullptr, nullptr, ATT, g2, be2, IMGB,
                                           nullptr, COMB);
  // G5: h = gelu(comb @ wf1^T + b_ffn1)
  gemm256<1, 1><<<dim3(1024), blk512, 0, stream>>>(COMB, wf1b, b_ffn1, H, E, 4 * E, 16);
  // G6: ffn = h @ wf2^T + b_ffn2 -> d_out (f32)
  gemm256<0, 0><<<dim3(256), blk512, 0, stream>>>(H, wf2b, b_ffn2, d_out, 4 * E, E, 4);
  // LN3: out = LN(comb + ffn), in place on d_out
  ln_k<2><<<dim3(BROWS), blk, 0, stream>>>(nullptr, COMB, (float*)d_out, nullptr, g3, be3,
                                           nullptr, (float*)d_out, nullptr);
}